// Round 10
// baseline (189.715 us; speedup 1.0000x reference)
//
#include <hip/hip_runtime.h>
#include <math.h>

// Problem constants (match reference)
constexpr int Nn   = 8192;
constexpr int Ee   = 4096;
constexpr int DIN  = 256;
constexpr int DOUT = 128;
constexpr int NNZ  = 65536;
constexpr int EC   = 96;   // capacity: nodes per edge (deg ~ Poisson(16))
constexpr int NC   = 48;   // capacity: edges per node (deg ~ Poisson(8))

#define TEMPR 0.08838834764831845f   // 1/sqrt(128)
#define EM1   1.7182818284590452f    // e - 1

typedef __attribute__((ext_vector_type(8))) short short8;
typedef __attribute__((ext_vector_type(4))) float f32x4;

static __device__ __forceinline__ float wave_sum64(float v) {
#pragma unroll
    for (int m = 32; m; m >>= 1) v += __shfl_xor(v, m, 64);
    return v;
}
static __device__ __forceinline__ float wave_max64(float v) {
#pragma unroll
    for (int m = 32; m; m >>= 1) v = fmaxf(v, __shfl_xor(v, m, 64));
    return v;
}
static __device__ __forceinline__ short f2bf(float f) {
    union { float f; unsigned u; } v; v.f = f;
    const unsigned r = (v.u + 0x7FFFu + ((v.u >> 16) & 1u)) >> 16;
    return (short)r;
}
static __device__ __forceinline__ unsigned packbf2(float a, float b) {
    return ((unsigned)(unsigned short)f2bf(a)) |
           (((unsigned)(unsigned short)f2bf(b)) << 16);
}
static __device__ __forceinline__ float2 unpackbf2(unsigned u) {
    union { unsigned u; float f; } lo, hi;
    lo.u = u << 16; hi.u = u & 0xFFFF0000u;
    return make_float2(lo.f, hi.f);
}

// ---------------------------------------------------------------------------
// K0: prologue (also zeroes the accumulator/bitmap region -> no memset node).
//  blocks 0..31  : WW3 = W @ W3 (256x128) -> transposed-bf16 WWT[c][r]
//  blocks 32..39 : W2 transpose-bf16  W2T[n][k]
//  block  40     : bW3 = bias @ W3 (fp32)
//  blocks 41..104: zero z-region (uint4 strided)
// ---------------------------------------------------------------------------
__global__ __launch_bounds__(256) void k_ww3(
    const float* __restrict__ W, const float* __restrict__ W2,
    const float* __restrict__ W3, const float* __restrict__ bias,
    short* __restrict__ W2T, short* __restrict__ WWT, float* __restrict__ bW3,
    uint4* __restrict__ zb, unsigned zTot16)
{
    const int b = blockIdx.x;
    const int t = threadIdx.x;
    if (b < 32) {
        __shared__ float sW[8][128];
        const int r0 = b * 8;
        for (int i = t; i < 1024; i += 256)
            sW[i >> 7][i & 127] = W[(size_t)(r0 + (i >> 7)) * DOUT + (i & 127)];
        __syncthreads();
        const int c  = t & 127;
        const int rh = (t >> 7) * 4;
        float acc[4] = {0.f, 0.f, 0.f, 0.f};
        for (int k = 0; k < 128; ++k) {
            const float w3 = W3[(size_t)k * DOUT + c];
#pragma unroll
            for (int i = 0; i < 4; ++i) acc[i] = fmaf(sW[rh + i][k], w3, acc[i]);
        }
#pragma unroll
        for (int i = 0; i < 4; ++i)
            WWT[(size_t)c * DIN + (r0 + rh + i)] = f2bf(acc[i]);
    } else if (b < 40) {
        const int k0 = (b - 32) * 32;
        for (int i = t; i < 32 * 128; i += 256) {
            const int k = k0 + (i >> 7);
            const int n = i & 127;
            W2T[(size_t)n * DIN + k] = f2bf(W2[(size_t)k * DOUT + n]);
        }
    } else if (b == 40) {
        if (t < 128) {
            float acc = 0.f;
            for (int k = 0; k < 128; ++k)
                acc = fmaf(bias[k], W3[(size_t)k * DOUT + t], acc);
            bW3[t] = acc;
        }
    } else {
        uint4 z; z.x = z.y = z.z = z.w = 0u;
        for (unsigned i = (unsigned)(b - 41) * 256u + t; i < zTot16;
             i += 64u * 256u)
            zb[i] = z;
    }
}

// ---------------------------------------------------------------------------
// K1: MFMA GEMM  x4 = x@W2, xw = x@WW3 + bW3  -> interleaved bf16 pairs
//     xq[row][lane] = uint2{ x4 cols(2l,2l+1), xw cols(2l,2l+1) }
//     + CSR build + fp32 epilogues (rowv, colsums from exact accumulators).
// ---------------------------------------------------------------------------
__global__ __launch_bounds__(256) void k_gemm1f(
    const float* __restrict__ x, const short* __restrict__ W2T,
    const short* __restrict__ WWT, const float* __restrict__ bW3,
    const float* __restrict__ q, const int* __restrict__ hidx,
    unsigned* __restrict__ bitmap, int* __restrict__ degE, int* __restrict__ degN,
    int* __restrict__ csrEn, int* __restrict__ csrNe, int* __restrict__ csrNs,
    uint2* __restrict__ xq,
    float* __restrict__ rowv, float* __restrict__ csx4, float* __restrict__ csxw)
{
    __shared__ float s4[DOUT], sw[DOUT], srow[16];
    const int t    = threadIdx.x;
    const int lane = t & 63;
    const int wv   = t >> 6;
    const int n16  = lane & 15;
    const int quad = lane >> 4;
    const int r0   = blockIdx.x * 16;
    const int n0   = wv * 32;

    // ---- CSR build ----
    const unsigned gid = blockIdx.x * 256 + t;
    if (gid < NNZ) {
        const int n = hidx[gid];
        const int e = hidx[NNZ + gid];
        const unsigned word = (unsigned)n * (unsigned)Ee + (unsigned)e;
        const unsigned bit  = 1u << (word & 31u);
        const unsigned old  = atomicOr(&bitmap[word >> 5], bit);
        if (!(old & bit)) {
            const int pe = atomicAdd(&degE[e], 1);
            if (pe < EC) {
                csrEn[e * EC + pe] = n;
                const int pn = atomicAdd(&degN[n], 1);
                if (pn < NC) {
                    csrNe[n * NC + pn] = e;
                    csrNs[n * NC + pn] = e * EC + pe;
                }
            }
        }
    }

    // ---- MFMA main loop ----
    f32x4 acc4[2], accw[2];
#pragma unroll
    for (int nt = 0; nt < 2; ++nt) {
        acc4[nt] = (f32x4){0.f, 0.f, 0.f, 0.f};
        accw[nt] = (f32x4){0.f, 0.f, 0.f, 0.f};
    }
#pragma unroll
    for (int k0 = 0; k0 < DIN; k0 += 32) {
        const int kb = k0 + quad * 8;
        const float4 xa = *(const float4*)&x[(size_t)(r0 + n16) * DIN + kb];
        const float4 xb = *(const float4*)&x[(size_t)(r0 + n16) * DIN + kb + 4];
        short8 af;
        af[0] = f2bf(xa.x); af[1] = f2bf(xa.y); af[2] = f2bf(xa.z); af[3] = f2bf(xa.w);
        af[4] = f2bf(xb.x); af[5] = f2bf(xb.y); af[6] = f2bf(xb.z); af[7] = f2bf(xb.w);
#pragma unroll
        for (int nt = 0; nt < 2; ++nt) {
            const int col = n0 + nt * 16 + n16;
            const short8 b4 = *(const short8*)&W2T[(size_t)col * DIN + kb];
            const short8 bw = *(const short8*)&WWT[(size_t)col * DIN + kb];
            acc4[nt] = __builtin_amdgcn_mfma_f32_16x16x32_bf16(af, b4, acc4[nt], 0, 0, 0);
            accw[nt] = __builtin_amdgcn_mfma_f32_16x16x32_bf16(af, bw, accw[nt], 0, 0, 0);
        }
    }

    // ---- writeback (interleaved bf16 pairs via lane^1 shuffle) + epilogues --
    float bwv[2], qv[2];
#pragma unroll
    for (int nt = 0; nt < 2; ++nt) {
        const int col = n0 + nt * 16 + n16;
        bwv[nt] = bW3[col];
        qv[nt]  = q[col];
    }
#pragma unroll
    for (int nt = 0; nt < 2; ++nt) {
        const int col = n0 + nt * 16 + n16;
#pragma unroll
        for (int reg = 0; reg < 4; ++reg) {
            const int row = r0 + quad * 4 + reg;
            const float a4 = acc4[nt][reg];
            const float aw = accw[nt][reg] + bwv[nt];
            const float a4p = __shfl_xor(a4, 1, 64);
            const float awp = __shfl_xor(aw, 1, 64);
            if (!(n16 & 1)) {
                xq[(size_t)row * 64 + (col >> 1)] =
                    make_uint2(packbf2(a4, a4p), packbf2(aw, awp));
            }
        }
    }
    float pr[4];
#pragma unroll
    for (int reg = 0; reg < 4; ++reg)
        pr[reg] = qv[0] * acc4[0][reg] + qv[1] * acc4[1][reg];
#pragma unroll
    for (int m = 8; m; m >>= 1) {
#pragma unroll
        for (int reg = 0; reg < 4; ++reg) pr[reg] += __shfl_xor(pr[reg], m, 64);
    }
    if (t < 16) srow[t] = 0.f;
    if (t < DOUT) { s4[t] = 0.f; sw[t] = 0.f; }
    __syncthreads();
    if (n16 == 0) {
#pragma unroll
        for (int reg = 0; reg < 4; ++reg) atomicAdd(&srow[quad * 4 + reg], pr[reg]);
    }
#pragma unroll
    for (int nt = 0; nt < 2; ++nt) {
        const int col = n0 + nt * 16 + n16;
        const float c4s = acc4[nt][0] + acc4[nt][1] + acc4[nt][2] + acc4[nt][3];
        const float cws = accw[nt][0] + accw[nt][1] + accw[nt][2] + accw[nt][3]
                        + 4.f * bwv[nt];
        atomicAdd(&s4[col], c4s);
        atomicAdd(&sw[col], cws);
    }
    __syncthreads();
    if (t < 16) rowv[r0 + t] = srow[t] * TEMPR;
    if (t < DOUT) { atomicAdd(&csx4[t], s4[t]); atomicAdd(&csxw[t], sw[t]); }
}

// ---------------------------------------------------------------------------
// K2: per-edge: softmax1 -> Sval + ws scatter + c2; ONE uint2 load per
//     neighbor (x4|xw pair). Outputs: e4b (own array), gq.x = G1 pair.
// ---------------------------------------------------------------------------
__global__ __launch_bounds__(256) void k_edge1(
    const int* __restrict__ degE, const int* __restrict__ csrEn,
    const float* __restrict__ rowv,
    const float* __restrict__ csx4, const float* __restrict__ csxw,
    const uint2* __restrict__ xq,
    float* __restrict__ Sval, unsigned* __restrict__ e4b, uint2* __restrict__ gq,
    float* __restrict__ wsArr, float* __restrict__ c2g)
{
    __shared__ int   sN[4][EC];
    __shared__ float sS[4][EC];
    __shared__ float sC2[4];
    const int t    = threadIdx.x;
    const int w    = t >> 6;
    const int lane = t & 63;
    const int e    = blockIdx.x * 4 + w;
    const int deg  = min(degE[e], EC);
    const float ue = deg ? 1.0f / ((float)Nn + (float)deg * EM1) : 2.0f / (float)Nn;

    int   n0 = 0, n1 = 0;
    float r0 = -INFINITY, r1 = -INFINITY;
    if (lane < deg)      { n0 = csrEn[e * EC + lane];      r0 = rowv[n0]; }
    if (lane + 64 < deg) { n1 = csrEn[e * EC + lane + 64]; r1 = rowv[n1]; }
    const float m  = wave_max64(fmaxf(r0, r1));
    const float e0 = (lane < deg)      ? expf(r0 - m) : 0.f;
    const float e1 = (lane + 64 < deg) ? expf(r1 - m) : 0.f;
    const float Z  = wave_sum64(e0 + e1);
    const float inv = deg ? 1.0f / Z : 0.f;
    const float base = EM1 * ue;
    if (lane < deg) {
        const float sv = fmaf(e0, inv, base);
        sN[w][lane] = n0; sS[w][lane] = sv;
        Sval[e * EC + lane] = sv;
        atomicAdd(&wsArr[n0], ue * sv);
    }
    if (lane + 64 < deg) {
        const float sv = fmaf(e1, inv, base);
        sN[w][lane + 64] = n1; sS[w][lane + 64] = sv;
        Sval[e * EC + lane + 64] = sv;
        atomicAdd(&wsArr[n1], ue * sv);
    }

    const float2 cw = *(const float2*)&csxw[lane * 2];
    const float2 c4 = *(const float2*)&csx4[lane * 2];
    float2 aE = make_float2(ue * cw.x, ue * cw.y);
    float2 aG = make_float2(ue * c4.x, ue * c4.y);
    int j = 0;
    for (; j + 8 <= deg; j += 8) {
        int ai[8]; float bi[8]; uint2 u[8];
#pragma unroll
        for (int k = 0; k < 8; ++k) { ai[k] = sN[w][j+k]; bi[k] = sS[w][j+k]; }
#pragma unroll
        for (int k = 0; k < 8; ++k)
            u[k] = xq[(size_t)ai[k] * 64 + lane];
#pragma unroll
        for (int k = 0; k < 8; ++k) {
            const float2 fv = unpackbf2(u[k].x);
            const float2 tv = unpackbf2(u[k].y);
            aE.x = fmaf(bi[k], tv.x, aE.x); aE.y = fmaf(bi[k], tv.y, aE.y);
            aG.x = fmaf(bi[k], fv.x, aG.x); aG.y = fmaf(bi[k], fv.y, aG.y);
        }
    }
    for (; j < deg; ++j) {
        const int   a = sN[w][j];
        const float b = sS[w][j];
        const uint2 u = xq[(size_t)a * 64 + lane];
        const float2 fv = unpackbf2(u.x);
        const float2 tv = unpackbf2(u.y);
        aE.x = fmaf(b, tv.x, aE.x); aE.y = fmaf(b, tv.y, aE.y);
        aG.x = fmaf(b, fv.x, aG.x); aG.y = fmaf(b, fv.y, aG.y);
    }
    e4b[(size_t)e * 64 + lane] = packbf2(aE.x, aE.y);
    ((unsigned*)gq)[((size_t)e * 64 + lane) * 2] = packbf2(aG.x, aG.y);

    if (lane == 0) sC2[w] = ue * ue;
    __syncthreads();
    if (t == 0) atomicAdd(c2g, sC2[0] + sC2[1] + sC2[2] + sC2[3]);
}

// ---------------------------------------------------------------------------
// K3: per-node softmax2 (lane-per-edge streaming dots over bf16 e4b rows)
//     -> Tval, v[n]; weighted colsum epilogues.
// ---------------------------------------------------------------------------
__global__ __launch_bounds__(256) void k_node2(
    const int* __restrict__ degN, const int* __restrict__ csrNe,
    const int* __restrict__ csrNs, const uint2* __restrict__ xq,
    const unsigned* __restrict__ e4b, const float* __restrict__ wsArr,
    float* __restrict__ Tval, float* __restrict__ vArr,
    float* __restrict__ vxg, float* __restrict__ twxg, float* __restrict__ wsxg)
{
    __shared__ float sx[4][DOUT];
    __shared__ float sVX[DOUT], sTX[DOUT], sWX[DOUT];
    const int t    = threadIdx.x;
    const int w    = t >> 6;
    const int lane = t & 63;
    const unsigned* xqu = (const unsigned*)xq;

    float2 vxa = {0,0}, twa = {0,0}, wsa = {0,0};
#pragma unroll
    for (int s = 0; s < 2; ++s) {
        const int n   = blockIdx.x * 8 + w * 2 + s;
        const int deg = min(degN[n], NC);
        const float vn = deg ? 1.0f / ((float)Ee + (float)deg * EM1) : 2.0f / (float)Ee;
        const float2 xv = unpackbf2(xqu[((size_t)n * 64 + lane) * 2]);
        sx[w][lane * 2 + 0] = xv.x;
        sx[w][lane * 2 + 1] = xv.y;
        __builtin_amdgcn_s_waitcnt(0);     // own-wave LDS writes visible
        int ej = 0, slot = 0;
        if (lane < deg) { ej = csrNe[n * NC + lane]; slot = csrNs[n * NC + lane]; }
        const uint4* er = (const uint4*)&e4b[(size_t)ej * 64];
        float dot = 0.f;
#pragma unroll
        for (int c0 = 0; c0 < 16; c0 += 8) {
            uint4 ev[8];
#pragma unroll
            for (int k = 0; k < 8; ++k) ev[k] = er[c0 + k];
#pragma unroll
            for (int k = 0; k < 8; ++k) {
                const int base = (c0 + k) * 8;
                const float2 e0 = unpackbf2(ev[k].x);
                const float2 e1 = unpackbf2(ev[k].y);
                const float2 e2 = unpackbf2(ev[k].z);
                const float2 e3 = unpackbf2(ev[k].w);
                dot = fmaf(e0.x, sx[w][base + 0], dot);
                dot = fmaf(e0.y, sx[w][base + 1], dot);
                dot = fmaf(e1.x, sx[w][base + 2], dot);
                dot = fmaf(e1.y, sx[w][base + 3], dot);
                dot = fmaf(e2.x, sx[w][base + 4], dot);
                dot = fmaf(e2.y, sx[w][base + 5], dot);
                dot = fmaf(e3.x, sx[w][base + 6], dot);
                dot = fmaf(e3.y, sx[w][base + 7], dot);
            }
        }
        const float sj = (lane < deg) ? dot * TEMPR : -INFINITY;
        const float m  = wave_max64(sj);
        const float ex = (lane < deg) ? expf(sj - m) : 0.f;
        const float Z  = wave_sum64(ex);
        if (lane < deg) Tval[slot] = fmaf(EM1, vn, ex / Z);
        if (lane == 0) vArr[n] = vn;
        const float tw  = deg ? fmaf((float)deg * EM1, vn, 1.0f) : 0.f;
        const float wsn = wsArr[n];
        vxa.x = fmaf(vn,  xv.x, vxa.x); vxa.y = fmaf(vn,  xv.y, vxa.y);
        twa.x = fmaf(tw,  xv.x, twa.x); twa.y = fmaf(tw,  xv.y, twa.y);
        wsa.x = fmaf(wsn, xv.x, wsa.x); wsa.y = fmaf(wsn, xv.y, wsa.y);
    }
    __syncthreads();
    if (t < DOUT) { sVX[t] = 0.f; sTX[t] = 0.f; sWX[t] = 0.f; }
    __syncthreads();
    atomicAdd(&sVX[lane*2+0], vxa.x); atomicAdd(&sVX[lane*2+1], vxa.y);
    atomicAdd(&sTX[lane*2+0], twa.x); atomicAdd(&sTX[lane*2+1], twa.y);
    atomicAdd(&sWX[lane*2+0], wsa.x); atomicAdd(&sWX[lane*2+1], wsa.y);
    __syncthreads();
    if (t < DOUT) {
        atomicAdd(&vxg[t],  sVX[t]);
        atomicAdd(&twxg[t], sTX[t]);
        atomicAdd(&wsxg[t], sWX[t]);
    }
}

// ---------------------------------------------------------------------------
// K4: per-edge: G2[e] = vx + sum_{n in e} T[e,n] * x4[n]  -> gq.y
//     (x4 read as stride-2 dword from xq)
// ---------------------------------------------------------------------------
__global__ __launch_bounds__(256) void k_g2(
    const int* __restrict__ degE, const int* __restrict__ csrEn,
    const float* __restrict__ Tval, const float* __restrict__ vxg,
    const uint2* __restrict__ xq, uint2* __restrict__ gq)
{
    const int t    = threadIdx.x;
    const int w    = t >> 6;
    const int lane = t & 63;
    const int e    = blockIdx.x * 4 + w;
    const int deg  = min(degE[e], EC);
    const unsigned* xqu = (const unsigned*)xq;
    float2 acc = *(const float2*)&vxg[lane * 2];
    int j = 0;
    for (; j + 8 <= deg; j += 8) {
        int ai[8]; float bi[8]; unsigned fu[8];
#pragma unroll
        for (int k = 0; k < 8; ++k) { ai[k] = csrEn[e*EC+j+k]; bi[k] = Tval[e*EC+j+k]; }
#pragma unroll
        for (int k = 0; k < 8; ++k)
            fu[k] = xqu[((size_t)ai[k] * 64 + lane) * 2];
#pragma unroll
        for (int k = 0; k < 8; ++k) {
            const float2 fv = unpackbf2(fu[k]);
            acc.x = fmaf(bi[k], fv.x, acc.x); acc.y = fmaf(bi[k], fv.y, acc.y);
        }
    }
    for (; j < deg; ++j) {
        const int   a = csrEn[e*EC+j];
        const float b = Tval[e*EC+j];
        const float2 fv = unpackbf2(xqu[((size_t)a * 64 + lane) * 2]);
        acc.x = fmaf(b, fv.x, acc.x); acc.y = fmaf(b, fv.y, acc.y);
    }
    ((unsigned*)gq)[((size_t)e * 64 + lane) * 2 + 1] = packbf2(acc.x, acc.y);
}

// ---------------------------------------------------------------------------
// K5: final per-node combine + elu — ONE uint2 load per neighbor (G1|G2 pair)
// ---------------------------------------------------------------------------
__global__ __launch_bounds__(256) void k_final(
    const int* __restrict__ degN, const int* __restrict__ csrNe,
    const int* __restrict__ csrNs, const float* __restrict__ Sval,
    const float* __restrict__ Tval, const float* __restrict__ vArr,
    const float* __restrict__ c2g, const float* __restrict__ csx4,
    const float* __restrict__ wsxg, const float* __restrict__ vxg,
    const float* __restrict__ twxg,
    const uint2* __restrict__ gq,
    float* __restrict__ out)
{
    const int t    = threadIdx.x;
    const int w    = t >> 6;
    const int lane = t & 63;
    const int n    = blockIdx.x * 4 + w;
    const int deg  = min(degN[n], NC);
    const float vn = vArr[n];
    const float c2 = *c2g;
    const float2 c4v = *(const float2*)&csx4[lane * 2];
    const float2 wsv = *(const float2*)&wsxg[lane * 2];
    const float2 vxv = *(const float2*)&vxg[lane * 2];
    const float2 twv = *(const float2*)&twxg[lane * 2];
    float2 acc;
    acc.x = fmaf(c2, c4v.x, wsv.x) + vn * fmaf((float)Ee, vxv.x, twv.x);
    acc.y = fmaf(c2, c4v.y, wsv.y) + vn * fmaf((float)Ee, vxv.y, twv.y);
    int j = 0;
    for (; j + 8 <= deg; j += 8) {
        int ei[8], si[8]; float sv[8], tv[8]; uint2 g[8];
#pragma unroll
        for (int k = 0; k < 8; ++k) {
            ei[k] = csrNe[n*NC+j+k]; si[k] = csrNs[n*NC+j+k];
        }
#pragma unroll
        for (int k = 0; k < 8; ++k) {
            sv[k] = Sval[si[k]]; tv[k] = Tval[si[k]];
            g[k]  = gq[(size_t)ei[k] * 64 + lane];
        }
#pragma unroll
        for (int k = 0; k < 8; ++k) {
            const float2 g1 = unpackbf2(g[k].x);
            const float2 g2 = unpackbf2(g[k].y);
            acc.x = fmaf(sv[k], g1.x, acc.x); acc.y = fmaf(sv[k], g1.y, acc.y);
            acc.x = fmaf(tv[k], g2.x, acc.x); acc.y = fmaf(tv[k], g2.y, acc.y);
        }
    }
    for (; j + 4 <= deg; j += 4) {
        int ei[4], si[4]; float sv[4], tv[4]; uint2 g[4];
#pragma unroll
        for (int k = 0; k < 4; ++k) {
            ei[k] = csrNe[n*NC+j+k]; si[k] = csrNs[n*NC+j+k];
        }
#pragma unroll
        for (int k = 0; k < 4; ++k) {
            sv[k] = Sval[si[k]]; tv[k] = Tval[si[k]];
            g[k]  = gq[(size_t)ei[k] * 64 + lane];
        }
#pragma unroll
        for (int k = 0; k < 4; ++k) {
            const float2 g1 = unpackbf2(g[k].x);
            const float2 g2 = unpackbf2(g[k].y);
            acc.x = fmaf(sv[k], g1.x, acc.x); acc.y = fmaf(sv[k], g1.y, acc.y);
            acc.x = fmaf(tv[k], g2.x, acc.x); acc.y = fmaf(tv[k], g2.y, acc.y);
        }
    }
    for (; j < deg; ++j) {
        const int ea = csrNe[n*NC+j];
        const int sa = csrNs[n*NC+j];
        const float sva = Sval[sa], tva = Tval[sa];
        const uint2 g = gq[(size_t)ea * 64 + lane];
        const float2 g1a = unpackbf2(g.x);
        const float2 g2a = unpackbf2(g.y);
        acc.x = fmaf(sva, g1a.x, acc.x); acc.y = fmaf(sva, g1a.y, acc.y);
        acc.x = fmaf(tva, g2a.x, acc.x); acc.y = fmaf(tva, g2a.y, acc.y);
    }
    acc.x = acc.x > 0.f ? acc.x : expm1f(acc.x);
    acc.y = acc.y > 0.f ? acc.y : expm1f(acc.y);
    *(float2*)&out[(size_t)n * DOUT + lane * 2] = acc;
}

// ---------------------------------------------------------------------------
extern "C" void kernel_launch(void* const* d_in, const int* in_sizes, int n_in,
                              void* d_out, int out_size, void* d_ws, size_t ws_size,
                              hipStream_t stream)
{
    const float* x    = (const float*)d_in[0];
    const float* W    = (const float*)d_in[1];
    const float* W2   = (const float*)d_in[2];
    const float* W3   = (const float*)d_in[3];
    const float* bias = (const float*)d_in[4];
    const float* q    = (const float*)d_in[5];
    const int*   hidx = (const int*)d_in[6];
    float* out = (float*)d_out;

    char* wsp = (char*)d_ws;
    size_t o = 0;
    auto take = [&](size_t bytes) {
        size_t r = o; o += (bytes + 255) & ~(size_t)255; return r;
    };
    // --- zero-initialized region (zeroed by k_ww3 blocks 41..104) ---
    unsigned* bitmap = (unsigned*)(wsp + take((size_t)Nn * Ee / 8));   // 4 MB
    int*   degE  = (int*)  (wsp + take((size_t)Ee * 4));
    int*   degN  = (int*)  (wsp + take((size_t)Nn * 4));
    float* wsArr = (float*)(wsp + take((size_t)Nn * 4));
    float* c2g   = (float*)(wsp + take(4));
    float* csx4  = (float*)(wsp + take(DOUT * 4));
    float* csxw  = (float*)(wsp + take(DOUT * 4));
    float* vxg   = (float*)(wsp + take(DOUT * 4));
    float* twxg  = (float*)(wsp + take(DOUT * 4));
    float* wsxg  = (float*)(wsp + take(DOUT * 4));
    const size_t zbytes = o;
    // --- fully-overwritten scratch ---
    uint2* xq    = (uint2*)(wsp + take((size_t)Nn * 64 * 8));   // x4|xw bf16 pairs, 4 MB
    float* rowv  = (float*)(wsp + take((size_t)Nn * 4));
    float* vArr  = (float*)(wsp + take((size_t)Nn * 4));
    int*   csrEn = (int*)  (wsp + take((size_t)Ee * EC * 4));
    float* Sval  = (float*)(wsp + take((size_t)Ee * EC * 4));
    float* Tval  = (float*)(wsp + take((size_t)Ee * EC * 4));
    int*   csrNe = (int*)  (wsp + take((size_t)Nn * NC * 4));
    int*   csrNs = (int*)  (wsp + take((size_t)Nn * NC * 4));
    unsigned* e4b = (unsigned*)(wsp + take((size_t)Ee * DOUT * 2));   // 1 MB
    uint2* gq    = (uint2*)(wsp + take((size_t)Ee * 64 * 8));   // G1|G2 pairs, 2 MB
    short* W2T   = (short*)(wsp + take((size_t)DOUT * DIN * 2));
    short* WWT   = (short*)(wsp + take((size_t)DOUT * DIN * 2));
    float* bW3   = (float*)(wsp + take(DOUT * 4));
    (void)ws_size; (void)in_sizes; (void)n_in; (void)out_size;

    k_ww3   <<<105,     256, 0, stream>>>(W, W2, W3, bias, W2T, WWT, bW3,
                                          (uint4*)d_ws, (unsigned)(zbytes / 16));
    k_gemm1f<<<Nn / 16, 256, 0, stream>>>(x, W2T, WWT, bW3, q, hidx,
                                          bitmap, degE, degN, csrEn, csrNe, csrNs,
                                          xq, rowv, csx4, csxw);
    k_edge1 <<<Ee / 4,  256, 0, stream>>>(degE, csrEn, rowv, csx4, csxw,
                                          xq, Sval, e4b, gq, wsArr, c2g);
    k_node2 <<<Nn / 8,  256, 0, stream>>>(degN, csrNe, csrNs, xq, e4b, wsArr,
                                          Tval, vArr, vxg, twxg, wsxg);
    k_g2    <<<Ee / 4,  256, 0, stream>>>(degE, csrEn, Tval, vxg, xq, gq);
    k_final <<<Nn / 4,  256, 0, stream>>>(degN, csrNe, csrNs, Sval, Tval, vArr,
                                          c2g, csx4, wsxg, vxg, twxg, gq, out);
}

// Round 11
// 183.697 us; speedup vs baseline: 1.0328x; 1.0328x over previous
//
#include <hip/hip_runtime.h>
#include <math.h>

// Problem constants (match reference)
constexpr int Nn   = 8192;
constexpr int Ee   = 4096;
constexpr int DIN  = 256;
constexpr int DOUT = 128;
constexpr int NNZ  = 65536;
constexpr int EC   = 96;   // capacity: nodes per edge (deg ~ Poisson(16))
constexpr int NC   = 48;   // capacity: edges per node (deg ~ Poisson(8))

#define TEMPR 0.08838834764831845f   // 1/sqrt(128)
#define EM1   1.7182818284590452f    // e - 1

typedef __attribute__((ext_vector_type(8))) short short8;
typedef __attribute__((ext_vector_type(4))) float f32x4;

static __device__ __forceinline__ float wave_sum64(float v) {
#pragma unroll
    for (int m = 32; m; m >>= 1) v += __shfl_xor(v, m, 64);
    return v;
}
static __device__ __forceinline__ float wave_max64(float v) {
#pragma unroll
    for (int m = 32; m; m >>= 1) v = fmaxf(v, __shfl_xor(v, m, 64));
    return v;
}
static __device__ __forceinline__ short f2bf(float f) {
    union { float f; unsigned u; } v; v.f = f;
    const unsigned r = (v.u + 0x7FFFu + ((v.u >> 16) & 1u)) >> 16;
    return (short)r;
}
static __device__ __forceinline__ unsigned packbf2(float a, float b) {
    return ((unsigned)(unsigned short)f2bf(a)) |
           (((unsigned)(unsigned short)f2bf(b)) << 16);
}
static __device__ __forceinline__ float2 unpackbf2(unsigned u) {
    union { unsigned u; float f; } lo, hi;
    lo.u = u << 16; hi.u = u & 0xFFFF0000u;
    return make_float2(lo.f, hi.f);
}

// ---------------------------------------------------------------------------
// K0: prologue (also zeroes the accumulator/bitmap region -> no memset node).
//  blocks 0..31  : WW3 = W @ W3 (256x128) -> transposed-bf16 WWT[c][r]
//  blocks 32..39 : W2 transpose-bf16  W2T[n][k]
//  block  40     : bW3 = bias @ W3 (fp32)
//  blocks 41..104: zero z-region (uint4 strided)
// ---------------------------------------------------------------------------
__global__ __launch_bounds__(256) void k_ww3(
    const float* __restrict__ W, const float* __restrict__ W2,
    const float* __restrict__ W3, const float* __restrict__ bias,
    short* __restrict__ W2T, short* __restrict__ WWT, float* __restrict__ bW3,
    uint4* __restrict__ zb, unsigned zTot16)
{
    const int b = blockIdx.x;
    const int t = threadIdx.x;
    if (b < 32) {
        __shared__ float sW[8][128];
        const int r0 = b * 8;
        for (int i = t; i < 1024; i += 256)
            sW[i >> 7][i & 127] = W[(size_t)(r0 + (i >> 7)) * DOUT + (i & 127)];
        __syncthreads();
        const int c  = t & 127;
        const int rh = (t >> 7) * 4;
        float acc[4] = {0.f, 0.f, 0.f, 0.f};
        for (int k = 0; k < 128; ++k) {
            const float w3 = W3[(size_t)k * DOUT + c];
#pragma unroll
            for (int i = 0; i < 4; ++i) acc[i] = fmaf(sW[rh + i][k], w3, acc[i]);
        }
#pragma unroll
        for (int i = 0; i < 4; ++i)
            WWT[(size_t)c * DIN + (r0 + rh + i)] = f2bf(acc[i]);
    } else if (b < 40) {
        const int k0 = (b - 32) * 32;
        for (int i = t; i < 32 * 128; i += 256) {
            const int k = k0 + (i >> 7);
            const int n = i & 127;
            W2T[(size_t)n * DIN + k] = f2bf(W2[(size_t)k * DOUT + n]);
        }
    } else if (b == 40) {
        if (t < 128) {
            float acc = 0.f;
            for (int k = 0; k < 128; ++k)
                acc = fmaf(bias[k], W3[(size_t)k * DOUT + t], acc);
            bW3[t] = acc;
        }
    } else {
        uint4 z; z.x = z.y = z.z = z.w = 0u;
        for (unsigned i = (unsigned)(b - 41) * 256u + t; i < zTot16;
             i += 64u * 256u)
            zb[i] = z;
    }
}

// ---------------------------------------------------------------------------
// K1: MFMA GEMM  x4 = x@W2, xw = x@WW3 + bW3  -> bf16 arrays x4b/xwb
//     + CSR build + fp32 epilogues (rowv from exact accumulators, colsums).
// ---------------------------------------------------------------------------
__global__ __launch_bounds__(256) void k_gemm1f(
    const float* __restrict__ x, const short* __restrict__ W2T,
    const short* __restrict__ WWT, const float* __restrict__ bW3,
    const float* __restrict__ q, const int* __restrict__ hidx,
    unsigned* __restrict__ bitmap, int* __restrict__ degE, int* __restrict__ degN,
    int* __restrict__ csrEn, int* __restrict__ csrNe, int* __restrict__ csrNs,
    short* __restrict__ x4b, short* __restrict__ xwb,
    float* __restrict__ rowv, float* __restrict__ csx4, float* __restrict__ csxw)
{
    __shared__ float s4[DOUT], sw[DOUT], srow[16];
    const int t    = threadIdx.x;
    const int lane = t & 63;
    const int wv   = t >> 6;
    const int n16  = lane & 15;
    const int quad = lane >> 4;
    const int r0   = blockIdx.x * 16;
    const int n0   = wv * 32;

    // ---- CSR build ----
    const unsigned gid = blockIdx.x * 256 + t;
    if (gid < NNZ) {
        const int n = hidx[gid];
        const int e = hidx[NNZ + gid];
        const unsigned word = (unsigned)n * (unsigned)Ee + (unsigned)e;
        const unsigned bit  = 1u << (word & 31u);
        const unsigned old  = atomicOr(&bitmap[word >> 5], bit);
        if (!(old & bit)) {
            const int pe = atomicAdd(&degE[e], 1);
            if (pe < EC) {
                csrEn[e * EC + pe] = n;
                const int pn = atomicAdd(&degN[n], 1);
                if (pn < NC) {
                    csrNe[n * NC + pn] = e;
                    csrNs[n * NC + pn] = e * EC + pe;
                }
            }
        }
    }

    // ---- MFMA main loop ----
    f32x4 acc4[2], accw[2];
#pragma unroll
    for (int nt = 0; nt < 2; ++nt) {
        acc4[nt] = (f32x4){0.f, 0.f, 0.f, 0.f};
        accw[nt] = (f32x4){0.f, 0.f, 0.f, 0.f};
    }
#pragma unroll
    for (int k0 = 0; k0 < DIN; k0 += 32) {
        const int kb = k0 + quad * 8;
        const float4 xa = *(const float4*)&x[(size_t)(r0 + n16) * DIN + kb];
        const float4 xb = *(const float4*)&x[(size_t)(r0 + n16) * DIN + kb + 4];
        short8 af;
        af[0] = f2bf(xa.x); af[1] = f2bf(xa.y); af[2] = f2bf(xa.z); af[3] = f2bf(xa.w);
        af[4] = f2bf(xb.x); af[5] = f2bf(xb.y); af[6] = f2bf(xb.z); af[7] = f2bf(xb.w);
#pragma unroll
        for (int nt = 0; nt < 2; ++nt) {
            const int col = n0 + nt * 16 + n16;
            const short8 b4 = *(const short8*)&W2T[(size_t)col * DIN + kb];
            const short8 bw = *(const short8*)&WWT[(size_t)col * DIN + kb];
            acc4[nt] = __builtin_amdgcn_mfma_f32_16x16x32_bf16(af, b4, acc4[nt], 0, 0, 0);
            accw[nt] = __builtin_amdgcn_mfma_f32_16x16x32_bf16(af, bw, accw[nt], 0, 0, 0);
        }
    }

    // ---- writeback (bf16) + epilogues (fp32) ----
    float bwv[2], qv[2];
#pragma unroll
    for (int nt = 0; nt < 2; ++nt) {
        const int col = n0 + nt * 16 + n16;
        bwv[nt] = bW3[col];
        qv[nt]  = q[col];
    }
#pragma unroll
    for (int nt = 0; nt < 2; ++nt) {
        const int col = n0 + nt * 16 + n16;
#pragma unroll
        for (int reg = 0; reg < 4; ++reg) {
            const int row = r0 + quad * 4 + reg;
            x4b[(size_t)row * DOUT + col] = f2bf(acc4[nt][reg]);
            xwb[(size_t)row * DOUT + col] = f2bf(accw[nt][reg] + bwv[nt]);
        }
    }
    float pr[4];
#pragma unroll
    for (int reg = 0; reg < 4; ++reg)
        pr[reg] = qv[0] * acc4[0][reg] + qv[1] * acc4[1][reg];
#pragma unroll
    for (int m = 8; m; m >>= 1) {
#pragma unroll
        for (int reg = 0; reg < 4; ++reg) pr[reg] += __shfl_xor(pr[reg], m, 64);
    }
    if (t < 16) srow[t] = 0.f;
    if (t < DOUT) { s4[t] = 0.f; sw[t] = 0.f; }
    __syncthreads();
    if (n16 == 0) {
#pragma unroll
        for (int reg = 0; reg < 4; ++reg) atomicAdd(&srow[quad * 4 + reg], pr[reg]);
    }
#pragma unroll
    for (int nt = 0; nt < 2; ++nt) {
        const int col = n0 + nt * 16 + n16;
        const float c4s = acc4[nt][0] + acc4[nt][1] + acc4[nt][2] + acc4[nt][3];
        const float cws = accw[nt][0] + accw[nt][1] + accw[nt][2] + accw[nt][3]
                        + 4.f * bwv[nt];
        atomicAdd(&s4[col], c4s);
        atomicAdd(&sw[col], cws);
    }
    __syncthreads();
    if (t < 16) rowv[r0 + t] = srow[t] * TEMPR;
    if (t < DOUT) { atomicAdd(&csx4[t], s4[t]); atomicAdd(&csxw[t], sw[t]); }
}

// ---------------------------------------------------------------------------
// K2: per-edge: softmax1 -> Sval + ws scatter + c2; bf16 gathers:
//     e4b = att1 @ xw,  G1b = att1 @ x4
// ---------------------------------------------------------------------------
__global__ __launch_bounds__(256) void k_edge1(
    const int* __restrict__ degE, const int* __restrict__ csrEn,
    const float* __restrict__ rowv,
    const float* __restrict__ csx4, const float* __restrict__ csxw,
    const unsigned* __restrict__ x4b, const unsigned* __restrict__ xwb,
    float* __restrict__ Sval, unsigned* __restrict__ e4b, unsigned* __restrict__ G1b,
    float* __restrict__ wsArr, float* __restrict__ c2g)
{
    __shared__ int   sN[4][EC];
    __shared__ float sS[4][EC];
    __shared__ float sC2[4];
    const int t    = threadIdx.x;
    const int w    = t >> 6;
    const int lane = t & 63;
    const int e    = blockIdx.x * 4 + w;
    const int deg  = min(degE[e], EC);
    const float ue = deg ? 1.0f / ((float)Nn + (float)deg * EM1) : 2.0f / (float)Nn;

    int   n0 = 0, n1 = 0;
    float r0 = -INFINITY, r1 = -INFINITY;
    if (lane < deg)      { n0 = csrEn[e * EC + lane];      r0 = rowv[n0]; }
    if (lane + 64 < deg) { n1 = csrEn[e * EC + lane + 64]; r1 = rowv[n1]; }
    const float m  = wave_max64(fmaxf(r0, r1));
    const float e0 = (lane < deg)      ? expf(r0 - m) : 0.f;
    const float e1 = (lane + 64 < deg) ? expf(r1 - m) : 0.f;
    const float Z  = wave_sum64(e0 + e1);
    const float inv = deg ? 1.0f / Z : 0.f;
    const float base = EM1 * ue;
    if (lane < deg) {
        const float sv = fmaf(e0, inv, base);
        sN[w][lane] = n0; sS[w][lane] = sv;
        Sval[e * EC + lane] = sv;
        atomicAdd(&wsArr[n0], ue * sv);
    }
    if (lane + 64 < deg) {
        const float sv = fmaf(e1, inv, base);
        sN[w][lane + 64] = n1; sS[w][lane + 64] = sv;
        Sval[e * EC + lane + 64] = sv;
        atomicAdd(&wsArr[n1], ue * sv);
    }

    const float2 cw = *(const float2*)&csxw[lane * 2];
    const float2 c4 = *(const float2*)&csx4[lane * 2];
    float2 aE = make_float2(ue * cw.x, ue * cw.y);
    float2 aG = make_float2(ue * c4.x, ue * c4.y);
    int j = 0;
    for (; j + 8 <= deg; j += 8) {
        int ai[8]; float bi[8]; unsigned tu[8], fu[8];
#pragma unroll
        for (int k = 0; k < 8; ++k) { ai[k] = sN[w][j+k]; bi[k] = sS[w][j+k]; }
#pragma unroll
        for (int k = 0; k < 8; ++k) {
            tu[k] = xwb[(size_t)ai[k] * 64 + lane];
            fu[k] = x4b[(size_t)ai[k] * 64 + lane];
        }
#pragma unroll
        for (int k = 0; k < 8; ++k) {
            const float2 tv = unpackbf2(tu[k]);
            const float2 fv = unpackbf2(fu[k]);
            aE.x = fmaf(bi[k], tv.x, aE.x); aE.y = fmaf(bi[k], tv.y, aE.y);
            aG.x = fmaf(bi[k], fv.x, aG.x); aG.y = fmaf(bi[k], fv.y, aG.y);
        }
    }
    for (; j < deg; ++j) {
        const int   a = sN[w][j];
        const float b = sS[w][j];
        const float2 tv = unpackbf2(xwb[(size_t)a * 64 + lane]);
        const float2 fv = unpackbf2(x4b[(size_t)a * 64 + lane]);
        aE.x = fmaf(b, tv.x, aE.x); aE.y = fmaf(b, tv.y, aE.y);
        aG.x = fmaf(b, fv.x, aG.x); aG.y = fmaf(b, fv.y, aG.y);
    }
    e4b[(size_t)e * 64 + lane] = packbf2(aE.x, aE.y);
    G1b[(size_t)e * 64 + lane] = packbf2(aG.x, aG.y);

    if (lane == 0) sC2[w] = ue * ue;
    __syncthreads();
    if (t == 0) atomicAdd(c2g, sC2[0] + sC2[1] + sC2[2] + sC2[3]);
}

// ---------------------------------------------------------------------------
// K3: per-node softmax2 (lane-per-edge streaming dots over bf16 e4b rows)
//     -> Tval, v[n]; weighted colsum epilogues. Per-wave LDS staging, no
//     cross-wave syncs in the node loop.
// ---------------------------------------------------------------------------
__global__ __launch_bounds__(256) void k_node2(
    const int* __restrict__ degN, const int* __restrict__ csrNe,
    const int* __restrict__ csrNs, const unsigned* __restrict__ x4b,
    const unsigned* __restrict__ e4b, const float* __restrict__ wsArr,
    float* __restrict__ Tval, float* __restrict__ vArr,
    float* __restrict__ vxg, float* __restrict__ twxg, float* __restrict__ wsxg)
{
    __shared__ float sx[4][DOUT];
    __shared__ float sVX[DOUT], sTX[DOUT], sWX[DOUT];
    const int t    = threadIdx.x;
    const int w    = t >> 6;
    const int lane = t & 63;

    float2 vxa = {0,0}, twa = {0,0}, wsa = {0,0};
#pragma unroll
    for (int s = 0; s < 2; ++s) {
        const int n   = blockIdx.x * 8 + w * 2 + s;
        const int deg = min(degN[n], NC);
        const float vn = deg ? 1.0f / ((float)Ee + (float)deg * EM1) : 2.0f / (float)Ee;
        const float2 xv = unpackbf2(x4b[(size_t)n * 64 + lane]);
        sx[w][lane * 2 + 0] = xv.x;
        sx[w][lane * 2 + 1] = xv.y;
        __builtin_amdgcn_s_waitcnt(0);     // own-wave LDS writes visible
        int ej = 0, slot = 0;
        if (lane < deg) { ej = csrNe[n * NC + lane]; slot = csrNs[n * NC + lane]; }
        const uint4* er = (const uint4*)&e4b[(size_t)ej * 64];
        float dot = 0.f;
#pragma unroll
        for (int c0 = 0; c0 < 16; c0 += 8) {
            uint4 ev[8];
#pragma unroll
            for (int k = 0; k < 8; ++k) ev[k] = er[c0 + k];
#pragma unroll
            for (int k = 0; k < 8; ++k) {
                const int base = (c0 + k) * 8;
                const float2 e0 = unpackbf2(ev[k].x);
                const float2 e1 = unpackbf2(ev[k].y);
                const float2 e2 = unpackbf2(ev[k].z);
                const float2 e3 = unpackbf2(ev[k].w);
                dot = fmaf(e0.x, sx[w][base + 0], dot);
                dot = fmaf(e0.y, sx[w][base + 1], dot);
                dot = fmaf(e1.x, sx[w][base + 2], dot);
                dot = fmaf(e1.y, sx[w][base + 3], dot);
                dot = fmaf(e2.x, sx[w][base + 4], dot);
                dot = fmaf(e2.y, sx[w][base + 5], dot);
                dot = fmaf(e3.x, sx[w][base + 6], dot);
                dot = fmaf(e3.y, sx[w][base + 7], dot);
            }
        }
        const float sj = (lane < deg) ? dot * TEMPR : -INFINITY;
        const float m  = wave_max64(sj);
        const float ex = (lane < deg) ? expf(sj - m) : 0.f;
        const float Z  = wave_sum64(ex);
        if (lane < deg) Tval[slot] = fmaf(EM1, vn, ex / Z);
        if (lane == 0) vArr[n] = vn;
        const float tw  = deg ? fmaf((float)deg * EM1, vn, 1.0f) : 0.f;
        const float wsn = wsArr[n];
        vxa.x = fmaf(vn,  xv.x, vxa.x); vxa.y = fmaf(vn,  xv.y, vxa.y);
        twa.x = fmaf(tw,  xv.x, twa.x); twa.y = fmaf(tw,  xv.y, twa.y);
        wsa.x = fmaf(wsn, xv.x, wsa.x); wsa.y = fmaf(wsn, xv.y, wsa.y);
    }
    __syncthreads();
    if (t < DOUT) { sVX[t] = 0.f; sTX[t] = 0.f; sWX[t] = 0.f; }
    __syncthreads();
    atomicAdd(&sVX[lane*2+0], vxa.x); atomicAdd(&sVX[lane*2+1], vxa.y);
    atomicAdd(&sTX[lane*2+0], twa.x); atomicAdd(&sTX[lane*2+1], twa.y);
    atomicAdd(&sWX[lane*2+0], wsa.x); atomicAdd(&sWX[lane*2+1], wsa.y);
    __syncthreads();
    if (t < DOUT) {
        atomicAdd(&vxg[t],  sVX[t]);
        atomicAdd(&twxg[t], sTX[t]);
        atomicAdd(&wsxg[t], sWX[t]);
    }
}

// ---------------------------------------------------------------------------
// K4: per-edge: G2b[e] = vx + sum_{n in e} T[e,n] * x4[n]   (bf16 gather)
// ---------------------------------------------------------------------------
__global__ __launch_bounds__(256) void k_g2(
    const int* __restrict__ degE, const int* __restrict__ csrEn,
    const float* __restrict__ Tval, const float* __restrict__ vxg,
    const unsigned* __restrict__ x4b, unsigned* __restrict__ G2b)
{
    const int t    = threadIdx.x;
    const int w    = t >> 6;
    const int lane = t & 63;
    const int e    = blockIdx.x * 4 + w;
    const int deg  = min(degE[e], EC);
    float2 acc = *(const float2*)&vxg[lane * 2];
    int j = 0;
    for (; j + 8 <= deg; j += 8) {
        int ai[8]; float bi[8]; unsigned fu[8];
#pragma unroll
        for (int k = 0; k < 8; ++k) { ai[k] = csrEn[e*EC+j+k]; bi[k] = Tval[e*EC+j+k]; }
#pragma unroll
        for (int k = 0; k < 8; ++k)
            fu[k] = x4b[(size_t)ai[k] * 64 + lane];
#pragma unroll
        for (int k = 0; k < 8; ++k) {
            const float2 fv = unpackbf2(fu[k]);
            acc.x = fmaf(bi[k], fv.x, acc.x); acc.y = fmaf(bi[k], fv.y, acc.y);
        }
    }
    for (; j < deg; ++j) {
        const int   a = csrEn[e*EC+j];
        const float b = Tval[e*EC+j];
        const float2 fv = unpackbf2(x4b[(size_t)a * 64 + lane]);
        acc.x = fmaf(b, fv.x, acc.x); acc.y = fmaf(b, fv.y, acc.y);
    }
    G2b[(size_t)e * 64 + lane] = packbf2(acc.x, acc.y);
}

// ---------------------------------------------------------------------------
// K5: final per-node combine + elu  (bf16 gathers of G1b/G2b)
// ---------------------------------------------------------------------------
__global__ __launch_bounds__(256) void k_final(
    const int* __restrict__ degN, const int* __restrict__ csrNe,
    const int* __restrict__ csrNs, const float* __restrict__ Sval,
    const float* __restrict__ Tval, const float* __restrict__ vArr,
    const float* __restrict__ c2g, const float* __restrict__ csx4,
    const float* __restrict__ wsxg, const float* __restrict__ vxg,
    const float* __restrict__ twxg,
    const unsigned* __restrict__ G1b, const unsigned* __restrict__ G2b,
    float* __restrict__ out)
{
    const int t    = threadIdx.x;
    const int w    = t >> 6;
    const int lane = t & 63;
    const int n    = blockIdx.x * 4 + w;
    const int deg  = min(degN[n], NC);
    const float vn = vArr[n];
    const float c2 = *c2g;
    const float2 c4v = *(const float2*)&csx4[lane * 2];
    const float2 wsv = *(const float2*)&wsxg[lane * 2];
    const float2 vxv = *(const float2*)&vxg[lane * 2];
    const float2 twv = *(const float2*)&twxg[lane * 2];
    float2 acc;
    acc.x = fmaf(c2, c4v.x, wsv.x) + vn * fmaf((float)Ee, vxv.x, twv.x);
    acc.y = fmaf(c2, c4v.y, wsv.y) + vn * fmaf((float)Ee, vxv.y, twv.y);
    int j = 0;
    for (; j + 4 <= deg; j += 4) {
        int ei[4], si[4]; float sv[4], tv[4]; unsigned g1u[4], g2u[4];
#pragma unroll
        for (int k = 0; k < 4; ++k) {
            ei[k] = csrNe[n*NC+j+k]; si[k] = csrNs[n*NC+j+k];
        }
#pragma unroll
        for (int k = 0; k < 4; ++k) {
            sv[k] = Sval[si[k]]; tv[k] = Tval[si[k]];
            g1u[k] = G1b[(size_t)ei[k] * 64 + lane];
            g2u[k] = G2b[(size_t)ei[k] * 64 + lane];
        }
#pragma unroll
        for (int k = 0; k < 4; ++k) {
            const float2 g1 = unpackbf2(g1u[k]);
            const float2 g2 = unpackbf2(g2u[k]);
            acc.x = fmaf(sv[k], g1.x, acc.x); acc.y = fmaf(sv[k], g1.y, acc.y);
            acc.x = fmaf(tv[k], g2.x, acc.x); acc.y = fmaf(tv[k], g2.y, acc.y);
        }
    }
    for (; j < deg; ++j) {
        const int ea = csrNe[n*NC+j];
        const int sa = csrNs[n*NC+j];
        const float sva = Sval[sa], tva = Tval[sa];
        const float2 g1a = unpackbf2(G1b[(size_t)ea * 64 + lane]);
        const float2 g2a = unpackbf2(G2b[(size_t)ea * 64 + lane]);
        acc.x = fmaf(sva, g1a.x, acc.x); acc.y = fmaf(sva, g1a.y, acc.y);
        acc.x = fmaf(tva, g2a.x, acc.x); acc.y = fmaf(tva, g2a.y, acc.y);
    }
    acc.x = acc.x > 0.f ? acc.x : expm1f(acc.x);
    acc.y = acc.y > 0.f ? acc.y : expm1f(acc.y);
    *(float2*)&out[(size_t)n * DOUT + lane * 2] = acc;
}

// ---------------------------------------------------------------------------
extern "C" void kernel_launch(void* const* d_in, const int* in_sizes, int n_in,
                              void* d_out, int out_size, void* d_ws, size_t ws_size,
                              hipStream_t stream)
{
    const float* x    = (const float*)d_in[0];
    const float* W    = (const float*)d_in[1];
    const float* W2   = (const float*)d_in[2];
    const float* W3   = (const float*)d_in[3];
    const float* bias = (const float*)d_in[4];
    const float* q    = (const float*)d_in[5];
    const int*   hidx = (const int*)d_in[6];
    float* out = (float*)d_out;

    char* wsp = (char*)d_ws;
    size_t o = 0;
    auto take = [&](size_t bytes) {
        size_t r = o; o += (bytes + 255) & ~(size_t)255; return r;
    };
    // --- zero-initialized region (zeroed by k_ww3 blocks 41..104) ---
    unsigned* bitmap = (unsigned*)(wsp + take((size_t)Nn * Ee / 8));   // 4 MB
    int*   degE  = (int*)  (wsp + take((size_t)Ee * 4));
    int*   degN  = (int*)  (wsp + take((size_t)Nn * 4));
    float* wsArr = (float*)(wsp + take((size_t)Nn * 4));
    float* c2g   = (float*)(wsp + take(4));
    float* csx4  = (float*)(wsp + take(DOUT * 4));
    float* csxw  = (float*)(wsp + take(DOUT * 4));
    float* vxg   = (float*)(wsp + take(DOUT * 4));
    float* twxg  = (float*)(wsp + take(DOUT * 4));
    float* wsxg  = (float*)(wsp + take(DOUT * 4));
    const size_t zbytes = o;
    // --- fully-overwritten scratch ---
    short* x4b   = (short*)(wsp + take((size_t)Nn * DOUT * 2));   // bf16
    short* xwb   = (short*)(wsp + take((size_t)Nn * DOUT * 2));   // bf16
    float* rowv  = (float*)(wsp + take((size_t)Nn * 4));
    float* vArr  = (float*)(wsp + take((size_t)Nn * 4));
    int*   csrEn = (int*)  (wsp + take((size_t)Ee * EC * 4));
    float* Sval  = (float*)(wsp + take((size_t)Ee * EC * 4));
    float* Tval  = (float*)(wsp + take((size_t)Ee * EC * 4));
    int*   csrNe = (int*)  (wsp + take((size_t)Nn * NC * 4));
    int*   csrNs = (int*)  (wsp + take((size_t)Nn * NC * 4));
    unsigned* e4b = (unsigned*)(wsp + take((size_t)Ee * DOUT * 2));   // bf16
    unsigned* G1b = (unsigned*)(wsp + take((size_t)Ee * DOUT * 2));   // bf16
    unsigned* G2b = (unsigned*)(wsp + take((size_t)Ee * DOUT * 2));   // bf16
    short* W2T   = (short*)(wsp + take((size_t)DOUT * DIN * 2));   // bf16 [n][k]
    short* WWT   = (short*)(wsp + take((size_t)DOUT * DIN * 2));   // bf16 [c][r]
    float* bW3   = (float*)(wsp + take(DOUT * 4));
    (void)ws_size; (void)in_sizes; (void)n_in; (void)out_size;

    k_ww3   <<<105,     256, 0, stream>>>(W, W2, W3, bias, W2T, WWT, bW3,
                                          (uint4*)d_ws, (unsigned)(zbytes / 16));
    k_gemm1f<<<Nn / 16, 256, 0, stream>>>(x, W2T, WWT, bW3, q, hidx,
                                          bitmap, degE, degN, csrEn, csrNe, csrNs,
                                          x4b, xwb, rowv, csx4, csxw);
    k_edge1 <<<Ee / 4,  256, 0, stream>>>(degE, csrEn, rowv, csx4, csxw,
                                          (const unsigned*)x4b, (const unsigned*)xwb,
                                          Sval, e4b, G1b, wsArr, c2g);
    k_node2 <<<Nn / 8,  256, 0, stream>>>(degN, csrNe, csrNs,
                                          (const unsigned*)x4b, e4b, wsArr,
                                          Tval, vArr, vxg, twxg, wsxg);
    k_g2    <<<Ee / 4,  256, 0, stream>>>(degE, csrEn, Tval, vxg,
                                          (const unsigned*)x4b, G2b);
    k_final <<<Nn / 4,  256, 0, stream>>>(degN, csrNe, csrNs, Sval, Tval, vArr,
                                          c2g, csx4, wsxg, vxg, twxg, G1b, G2b, out);
}